// Round 4
// baseline (185.322 us; speedup 1.0000x reference)
//
#include <hip/hip_runtime.h>

#define B_SZ 16384
#define D_SZ 256
#define C_SZ 2000
#define C_PAD 2048
#define MARGIN_F 1.0f

typedef __bf16 bf16x8 __attribute__((ext_vector_type(8)));
typedef float floatx4 __attribute__((ext_vector_type(4)));

// Fragment-major layouts (16x16x32 bf16 MFMA):
//   chunk(tile, ks, lane) -> 8 bf16 at base + ((tile*8 + ks)*64 + lane)*8
//   lane holds  M[tile*16 + (lane&15)][ks*32 + (lane>>4)*8 + j]  j=0..7
// predf: 1024 row-tiles * 8 ks * 64 lanes; sigf: 128 col-tiles * 8 ks * 64.

// ---- sig (D x C) fp32 -> sigf frag-major bf16, zero-pad cols >= C ----
__global__ __launch_bounds__(256) void convert_sigf_kernel(
    const float* __restrict__ sig, __bf16* __restrict__ sigf) {
  int t = blockIdx.x * 256 + threadIdx.x;   // 65536 chunks
  int lane = t & 63;
  int ks = (t >> 6) & 7;
  int ctg = t >> 9;
  int col = ctg * 16 + (lane & 15);
  int kb = ks * 32 + (lane >> 4) * 8;
  bf16x8 o;
  if (col < C_SZ) {
#pragma unroll
    for (int j = 0; j < 8; j++) o[j] = (__bf16)sig[(size_t)(kb + j) * C_SZ + col];
  } else {
#pragma unroll
    for (int j = 0; j < 8; j++) o[j] = (__bf16)0.f;
  }
  *(bf16x8*)(sigf + (size_t)t * 8) = o;
}

// ---- pred (B x D) fp32 -> predf frag-major bf16 ----
__global__ __launch_bounds__(256) void convert_predf_kernel(
    const float* __restrict__ pred, __bf16* __restrict__ predf) {
  int t = blockIdx.x * 256 + threadIdx.x;   // 524288 chunks
  int lane = t & 63;
  int ks = (t >> 6) & 7;
  int rt = t >> 9;
  int row = rt * 16 + (lane & 15);
  int kb = ks * 32 + (lane >> 4) * 8;
  const float* src = pred + (size_t)row * D_SZ + kb;
  float4 v0 = *(const float4*)src;
  float4 v1 = *(const float4*)(src + 4);
  bf16x8 o;
  o[0] = (__bf16)v0.x; o[1] = (__bf16)v0.y; o[2] = (__bf16)v0.z; o[3] = (__bf16)v0.w;
  o[4] = (__bf16)v1.x; o[5] = (__bf16)v1.y; o[6] = (__bf16)v1.z; o[7] = (__bf16)v1.w;
  *(bf16x8*)(predf + (size_t)t * 8) = o;
}

// ---- gt[b] = dot(pred[b,:], sig[:,label[b]]) in exact fp32 ----
__global__ __launch_bounds__(256) void gt_kernel(
    const float* __restrict__ pred, const float* __restrict__ sig,
    const int* __restrict__ label, float* __restrict__ gt) {
  int row = (blockIdx.x * 256 + threadIdx.x) >> 6;
  int lane = threadIdx.x & 63;
  int lbl = label[row];
  float4 p = *(const float4*)(pred + (size_t)row * D_SZ + lane * 4);
  float sum = p.x * sig[(size_t)(lane * 4 + 0) * C_SZ + lbl] +
              p.y * sig[(size_t)(lane * 4 + 1) * C_SZ + lbl] +
              p.z * sig[(size_t)(lane * 4 + 2) * C_SZ + lbl] +
              p.w * sig[(size_t)(lane * 4 + 3) * C_SZ + lbl];
#pragma unroll
  for (int off = 32; off > 0; off >>= 1) sum += __shfl_down(sum, off, 64);
  if (lane == 0) gt[row] = sum;
}

// ---- GEMM + hinge, zero LDS / zero barriers in main loop ----
// 256 blocks; block b owns rows b*64..b*64+63, ALL 2048 cols.
// A-frags (4 row-tiles x 8 ksteps = 128 VGPR/lane) held in registers.
// Wave w streams col-tiles w*32..w*32+31 from L2-resident sigf.
__global__ __launch_bounds__(256) void mfma_fused_kernel(
    const __bf16* __restrict__ predf, const __bf16* __restrict__ sigf,
    const int* __restrict__ label, const float* __restrict__ gt,
    float* __restrict__ out) {
  int tid = threadIdx.x;
  int lane = tid & 63;
  int w = tid >> 6;
  int quad = lane >> 4, lm = lane & 15;
  int row0 = blockIdx.x * 64;

  // A fragments: rows row0..row0+63, full K
  bf16x8 afr[4][8];
#pragma unroll
  for (int rt = 0; rt < 4; rt++)
#pragma unroll
    for (int ks = 0; ks < 8; ks++)
      afr[rt][ks] = *(const bf16x8*)(predf +
          ((size_t)((blockIdx.x * 4 + rt) * 8 + ks) * 64 + lane) * 8);

  // gt / label for the 16 output rows this lane owns (C/D: row=rt*16+quad*4+r)
  float gtv[16];
  int lbv[16];
#pragma unroll
  for (int rt = 0; rt < 4; rt++)
#pragma unroll
    for (int r = 0; r < 4; r++) {
      int rr = row0 + rt * 16 + quad * 4 + r;
      gtv[rt * 4 + r] = gt[rr];
      lbv[rt * 4 + r] = label[rr];
    }

  float sum = 0.f;
  for (int ct = 0; ct < 32; ct++) {
    int ctg = w * 32 + ct;
    floatx4 acc[4] = {};
#pragma unroll
    for (int ks = 0; ks < 8; ks++) {
      bf16x8 bfr = *(const bf16x8*)(sigf + ((size_t)(ctg * 8 + ks) * 64 + lane) * 8);
#pragma unroll
      for (int rt = 0; rt < 4; rt++)
        acc[rt] = __builtin_amdgcn_mfma_f32_16x16x32_bf16(afr[rt][ks], bfr, acc[rt], 0, 0, 0);
    }
    int col = ctg * 16 + lm;   // C/D layout: col=lane&15
    if (col < C_SZ) {
#pragma unroll
      for (int rt = 0; rt < 4; rt++)
#pragma unroll
        for (int r = 0; r < 4; r++) {
          float h = MARGIN_F + acc[rt][r] - gtv[rt * 4 + r];
          if (col != lbv[rt * 4 + r]) sum += fmaxf(h, 0.f);
        }
    }
  }
#pragma unroll
  for (int off = 32; off > 0; off >>= 1) sum += __shfl_down(sum, off, 64);
  if (lane == 0) atomicAdd(out, sum);
}

extern "C" void kernel_launch(void* const* d_in, const int* in_sizes, int n_in,
                              void* d_out, int out_size, void* d_ws, size_t ws_size,
                              hipStream_t stream) {
  const float* pred  = (const float*)d_in[0];   // (B, D) fp32
  const int*   label = (const int*)d_in[1];     // (B,)
  // d_in[2] = train_classes = arange(C), unused
  const float* sig   = (const float*)d_in[3];   // (D, C) fp32
  float* out = (float*)d_out;

  float*  gt    = (float*)d_ws;                                   // 64 KB
  __bf16* predf = (__bf16*)((char*)d_ws + (64 << 10));            // 8 MB
  __bf16* sigf  = (__bf16*)((char*)d_ws + (64 << 10) + (8 << 20));// 1 MB

  hipMemsetAsync(out, 0, sizeof(float), stream);
  convert_sigf_kernel<<<C_PAD / 16 * 8 * 64 / 256, 256, 0, stream>>>(sig, sigf);
  convert_predf_kernel<<<B_SZ / 16 * 8 * 64 / 256, 256, 0, stream>>>(pred, predf);
  gt_kernel<<<B_SZ / 4, 256, 0, stream>>>(pred, sig, label, gt);
  mfma_fused_kernel<<<B_SZ / 64, 256, 0, stream>>>(predf, sigf, label, gt, out);
}

// Round 5
// 165.910 us; speedup vs baseline: 1.1170x; 1.1170x over previous
//
#include <hip/hip_runtime.h>

#define B_SZ 16384
#define D_SZ 256
#define C_SZ 2000
#define C_PAD 2048
#define MARGIN_F 1.0f

typedef __bf16 bf16x8 __attribute__((ext_vector_type(8)));
typedef float floatx4 __attribute__((ext_vector_type(4)));

// Fragment-major layouts (16x16x32 bf16 MFMA):
//   chunk(tile, ks, lane) -> 8 bf16 at base + ((tile*8 + ks)*64 + lane)*8
//   lane holds  M[tile*16 + (lane&15)][ks*32 + (lane>>4)*8 + j]  j=0..7

// ---- sig (D x C) fp32 -> sigf frag-major bf16, zero-pad cols >= C ----
__global__ __launch_bounds__(256) void convert_sigf_kernel(
    const float* __restrict__ sig, __bf16* __restrict__ sigf) {
  int t = blockIdx.x * 256 + threadIdx.x;   // 65536 chunks
  int lane = t & 63;
  int ks = (t >> 6) & 7;
  int ctg = t >> 9;
  int col = ctg * 16 + (lane & 15);
  int kb = ks * 32 + (lane >> 4) * 8;
  bf16x8 o;
  if (col < C_SZ) {
#pragma unroll
    for (int j = 0; j < 8; j++) o[j] = (__bf16)sig[(size_t)(kb + j) * C_SZ + col];
  } else {
#pragma unroll
    for (int j = 0; j < 8; j++) o[j] = (__bf16)0.f;
  }
  *(bf16x8*)(sigf + (size_t)t * 8) = o;
}

// ---- fused: pred -> predf (frag-major bf16)  AND  gt (exact fp32) ----
// one wave per 16-row tile; pred rows are L1-hot for the gt pass
__global__ __launch_bounds__(256) void predf_gt_kernel(
    const float* __restrict__ pred, const float* __restrict__ sig,
    const int* __restrict__ label, __bf16* __restrict__ predf,
    float* __restrict__ gt) {
  int lane = threadIdx.x & 63;
  int g = blockIdx.x * 4 + (threadIdx.x >> 6);   // rowtile 0..1023
  // conversion: 8 ks-chunks cover rows g*16..g*16+15, full K
#pragma unroll
  for (int ks = 0; ks < 8; ks++) {
    int row = g * 16 + (lane & 15);
    int kb = ks * 32 + (lane >> 4) * 8;
    const float* src = pred + (size_t)row * D_SZ + kb;
    float4 v0 = *(const float4*)src;
    float4 v1 = *(const float4*)(src + 4);
    bf16x8 o;
    o[0] = (__bf16)v0.x; o[1] = (__bf16)v0.y; o[2] = (__bf16)v0.z; o[3] = (__bf16)v0.w;
    o[4] = (__bf16)v1.x; o[5] = (__bf16)v1.y; o[6] = (__bf16)v1.z; o[7] = (__bf16)v1.w;
    *(bf16x8*)(predf + ((size_t)(g * 8 + ks) * 64 + lane) * 8) = o;
  }
  // gt for the same 16 rows (pred row now in L1)
  for (int r = 0; r < 16; r++) {
    int row = g * 16 + r;
    int lbl = label[row];
    float4 p = *(const float4*)(pred + (size_t)row * D_SZ + lane * 4);
    float sum = p.x * sig[(size_t)(lane * 4 + 0) * C_SZ + lbl] +
                p.y * sig[(size_t)(lane * 4 + 1) * C_SZ + lbl] +
                p.z * sig[(size_t)(lane * 4 + 2) * C_SZ + lbl] +
                p.w * sig[(size_t)(lane * 4 + 3) * C_SZ + lbl];
#pragma unroll
    for (int off = 32; off > 0; off >>= 1) sum += __shfl_down(sum, off, 64);
    if (lane == 0) gt[row] = sum;
  }
}

// ---- GEMM + hinge: no LDS, no barriers, 1024 blocks for TLP ----
// block = 128 rows x 256 cols; 4 waves in 2x2; wave = 64 rows x 128 cols.
// A-frags (4 rowtiles x 8 ks = 128 VGPR/lane) loaded once; B streamed from
// L2-resident sigf (1 MB). colgroup = blockIdx & 7: the 8 blocks sharing
// A-rows dispatch to different XCDs concurrently (L3 serves A re-reads).
__global__ __launch_bounds__(256) void mfma_fused_kernel(
    const __bf16* __restrict__ predf, const __bf16* __restrict__ sigf,
    const int* __restrict__ label, const float* __restrict__ gt,
    float* __restrict__ out) {
  int tid = threadIdx.x;
  int lane = tid & 63;
  int w = tid >> 6;
  int wy = w >> 1, wx = w & 1;
  int quad = lane >> 4, lm = lane & 15;
  int blockRow = (int)blockIdx.x >> 3;
  int colgroup = (int)blockIdx.x & 7;

  // A fragments: 4 rowtiles (64 rows), full K
  bf16x8 afr[4][8];
#pragma unroll
  for (int rt = 0; rt < 4; rt++)
#pragma unroll
    for (int ks = 0; ks < 8; ks++)
      afr[rt][ks] = *(const bf16x8*)(predf +
          ((size_t)((blockRow * 8 + wy * 4 + rt) * 8 + ks) * 64 + lane) * 8);

  // gt/label for the 16 output rows this lane owns
  float gtv[16];
  int lbv[16];
#pragma unroll
  for (int rt = 0; rt < 4; rt++)
#pragma unroll
    for (int r = 0; r < 4; r++) {
      int rr = blockRow * 128 + wy * 64 + rt * 16 + quad * 4 + r;
      gtv[rt * 4 + r] = gt[rr];
      lbv[rt * 4 + r] = label[rr];
    }

  float sum = 0.f;
#pragma unroll
  for (int ct = 0; ct < 8; ct++) {
    int ctg = colgroup * 16 + wx * 8 + ct;
    floatx4 acc[4] = {};
#pragma unroll
    for (int ks = 0; ks < 8; ks++) {
      bf16x8 bfr = *(const bf16x8*)(sigf + ((size_t)(ctg * 8 + ks) * 64 + lane) * 8);
#pragma unroll
      for (int rt = 0; rt < 4; rt++)
        acc[rt] = __builtin_amdgcn_mfma_f32_16x16x32_bf16(afr[rt][ks], bfr, acc[rt], 0, 0, 0);
    }
    int col = ctg * 16 + lm;
    if (col < C_SZ) {
#pragma unroll
      for (int rt = 0; rt < 4; rt++)
#pragma unroll
        for (int r = 0; r < 4; r++) {
          float h = MARGIN_F + acc[rt][r] - gtv[rt * 4 + r];
          if (col != lbv[rt * 4 + r]) sum += fmaxf(h, 0.f);
        }
    }
  }
#pragma unroll
  for (int off = 32; off > 0; off >>= 1) sum += __shfl_down(sum, off, 64);
  if (lane == 0) atomicAdd(out, sum);
}

extern "C" void kernel_launch(void* const* d_in, const int* in_sizes, int n_in,
                              void* d_out, int out_size, void* d_ws, size_t ws_size,
                              hipStream_t stream) {
  const float* pred  = (const float*)d_in[0];   // (B, D) fp32
  const int*   label = (const int*)d_in[1];     // (B,)
  // d_in[2] = train_classes = arange(C), unused
  const float* sig   = (const float*)d_in[3];   // (D, C) fp32
  float* out = (float*)d_out;

  float*  gt    = (float*)d_ws;                                   // 64 KB
  __bf16* predf = (__bf16*)((char*)d_ws + (64 << 10));            // 8 MB
  __bf16* sigf  = (__bf16*)((char*)d_ws + (64 << 10) + (8 << 20));// 1 MB

  hipMemsetAsync(out, 0, sizeof(float), stream);
  convert_sigf_kernel<<<C_PAD / 16 * 8 * 64 / 256, 256, 0, stream>>>(sig, sigf);
  predf_gt_kernel<<<B_SZ / 64, 256, 0, stream>>>(pred, sig, label, predf, gt);
  mfma_fused_kernel<<<(B_SZ / 128) * (C_PAD / 256), 256, 0, stream>>>(
      predf, sigf, label, gt, out);
}